// Round 3
// baseline (133.760 us; speedup 1.0000x reference)
//
#include <hip/hip_runtime.h>
#include <math.h>

#define B 8
#define T 512
#define D 1024
#define H 16
#define DH 64

typedef __bf16 bf16;
typedef __attribute__((ext_vector_type(8))) __bf16 bf16x8;
typedef __attribute__((ext_vector_type(4))) __bf16 bf16x4;
typedef __attribute__((ext_vector_type(4))) float f32x4;

// Async global->LDS, 16 B per lane. LDS dest = wave-uniform base + lane*16.
__device__ __forceinline__ void gld16(const void* g, void* l) {
    __builtin_amdgcn_global_load_lds(
        (const __attribute__((address_space(1))) void*)g,
        (__attribute__((address_space(3))) void*)l, 16, 0, 0);
}

// MFMA 16x16x32 bf16 layouts (HW-verified per guide m89/m120):
//   A[m][k]: m = lane&15, k = (lane>>4)*8 + j
//   B[k][n]: n = lane&15, k = (lane>>4)*8 + j   (same lane map as A!)
//   C/D    : col = lane&15, row = (lane>>4)*4 + reg
// => swapping mfma operand order transposes D without touching fragments.
// LDS tiles are XOR-chunk swizzled: data chunk c of row r lives at LDS slot
// c ^ (r&7). gld16 staging achieves this with LINEAR global layout + source
// address offset ((lc ^ lr)*8)  [pre-swizzled-source pattern, m173].

#define EXP2SCALE 1.44269504088896f   // log2(e); folded into Q pre-scale

// ---------------------------------------------------------------------------
// Kernel 0: prep. blk<16: Wq -> per-head [e][d] bf16. blk<272: Wf -> [n][k]
// bf16. blk>=272 (512 blocks): K/V precompute — K[key][e], V^T[e][key] bf16
// per (b,h), computed once (R2 recomputed K/V per q-chunk = 4x waste).
// ---------------------------------------------------------------------------
__global__ __launch_bounds__(256) void prep(
    const float* __restrict__ X,
    const float* __restrict__ Wq, const float* __restrict__ Wk,
    const float* __restrict__ Wv, const float* __restrict__ Wf,
    bf16* __restrict__ WqT, bf16* __restrict__ WfT,
    bf16* __restrict__ Kg, bf16* __restrict__ Vg)
{
    __shared__ __align__(16) char smemP[34816];
    const int blk = blockIdx.x, tid = threadIdx.x;
    if (blk < 16) {
        bf16* Ts = (bf16*)smemP;   // 64x72
        const int h = blk;
        const float* src = Wq + h * 4096;
        bf16* dst = WqT + h * 4096;
        for (int i = tid; i < 1024; i += 256) {
            const int d = i >> 4, eq = (i & 15) * 4;
            const float4 w = *(const float4*)(src + d * 64 + eq);
            Ts[(eq + 0) * 72 + d] = (bf16)w.x; Ts[(eq + 1) * 72 + d] = (bf16)w.y;
            Ts[(eq + 2) * 72 + d] = (bf16)w.z; Ts[(eq + 3) * 72 + d] = (bf16)w.w;
        }
        __syncthreads();
        for (int i = tid; i < 512; i += 256) {
            const int e = i >> 3, kc = (i & 7) * 8;
            *(bf16x8*)(dst + e * 64 + kc) = *(const bf16x8*)&Ts[e * 72 + kc];
        }
    } else if (blk < 272) {
        bf16* Ts = (bf16*)smemP;
        const int ti = blk - 16, k0 = (ti >> 4) * 64, n0 = (ti & 15) * 64;
        for (int i = tid; i < 1024; i += 256) {
            const int k = i >> 4, nq = (i & 15) * 4;
            const float4 w = *(const float4*)(Wf + (size_t)(k0 + k) * D + n0 + nq);
            Ts[(nq + 0) * 72 + k] = (bf16)w.x; Ts[(nq + 1) * 72 + k] = (bf16)w.y;
            Ts[(nq + 2) * 72 + k] = (bf16)w.z; Ts[(nq + 3) * 72 + k] = (bf16)w.w;
        }
        __syncthreads();
        for (int i = tid; i < 512; i += 256) {
            const int n = i >> 3, kc = (i & 7) * 8;
            *(bf16x8*)(WfT + (size_t)(n0 + n) * D + k0 + kc) = *(const bf16x8*)&Ts[n * 72 + kc];
        }
    } else {
        // K/V precompute: (b, h, 128-key chunk)
        const int kb_ = blk - 272;
        const int b = kb_ >> 6, h = (kb_ >> 2) & 15, key0 = (kb_ & 3) * 128;
        const int bh = b * 16 + h;
        bf16* Xs  = (bf16*)smemP;                  // 128x64 swz (16384 B)
        bf16* Wks = (bf16*)(smemP + 16384);        // 64x72 (9216 B)
        bf16* Wvs = (bf16*)(smemP + 25600);        // 64x72
        const int wave = tid >> 6, lane = tid & 63;
        const int quad = lane >> 4, l15 = lane & 15;
        // stage X (keys key0..key0+127), bf16, swizzled
        for (int i = tid; i < 1024; i += 256) {
            const int row = i >> 3, c = i & 7;
            const float* s4 = X + (size_t)(b * T + key0 + row) * D + h * DH + c * 8;
            const float4 x0 = *(const float4*)s4;
            const float4 x1 = *(const float4*)(s4 + 4);
            bf16x8 t;
            t[0] = (bf16)x0.x; t[1] = (bf16)x0.y; t[2] = (bf16)x0.z; t[3] = (bf16)x0.w;
            t[4] = (bf16)x1.x; t[5] = (bf16)x1.y; t[6] = (bf16)x1.z; t[7] = (bf16)x1.w;
            *(bf16x8*)&Xs[row * 64 + ((c ^ (row & 7)) * 8)] = t;
        }
        // stage Wk, Wv transposed [e][d] p72
        for (int i = tid; i < 1024; i += 256) {
            const int d = i >> 4, eq = (i & 15) * 4;
            const float4 wk4 = *(const float4*)(Wk + h * 4096 + d * 64 + eq);
            Wks[(eq + 0) * 72 + d] = (bf16)wk4.x; Wks[(eq + 1) * 72 + d] = (bf16)wk4.y;
            Wks[(eq + 2) * 72 + d] = (bf16)wk4.z; Wks[(eq + 3) * 72 + d] = (bf16)wk4.w;
            const float4 wv4 = *(const float4*)(Wv + h * 4096 + d * 64 + eq);
            Wvs[(eq + 0) * 72 + d] = (bf16)wv4.x; Wvs[(eq + 1) * 72 + d] = (bf16)wv4.y;
            Wvs[(eq + 2) * 72 + d] = (bf16)wv4.z; Wvs[(eq + 3) * 72 + d] = (bf16)wv4.w;
        }
        __syncthreads();
        bf16x8 xf[2][2];   // [key-group kb][ks]; serves as A (V) and B (K)
#pragma unroll
        for (int kb = 0; kb < 2; ++kb)
#pragma unroll
            for (int ks = 0; ks < 2; ++ks)
                xf[kb][ks] = *(const bf16x8*)&Xs[(wave * 32 + kb * 16 + l15) * 64 +
                                                 (((ks * 4 + quad) ^ (l15 & 7)) * 8)];
        f32x4 accK[2][4] = {}, accV[2][4] = {};
#pragma unroll
        for (int ks = 0; ks < 2; ++ks)
#pragma unroll
            for (int nt = 0; nt < 4; ++nt) {
                const bf16x8 wk8 = *(const bf16x8*)&Wks[(nt * 16 + l15) * 72 + ks * 32 + quad * 8];
                const bf16x8 wv8 = *(const bf16x8*)&Wvs[(nt * 16 + l15) * 72 + ks * 32 + quad * 8];
#pragma unroll
                for (int kb = 0; kb < 2; ++kb) {
                    accK[kb][nt] = __builtin_amdgcn_mfma_f32_16x16x32_bf16(wk8, xf[kb][ks], accK[kb][nt], 0, 0, 0);
                    accV[kb][nt] = __builtin_amdgcn_mfma_f32_16x16x32_bf16(xf[kb][ks], wv8, accV[kb][nt], 0, 0, 0);
                }
            }
        const size_t base = (size_t)bh * 32768;
#pragma unroll
        for (int kb = 0; kb < 2; ++kb)
#pragma unroll
            for (int nt = 0; nt < 4; ++nt) {
                // K (swapped): accK[kb][nt][reg] = K[e=nt*16+quad*4+reg][key=key0+wave*32+kb*16+l15]
                const int keyK = key0 + wave * 32 + kb * 16 + l15;
                bf16x4 kp;
#pragma unroll
                for (int reg = 0; reg < 4; ++reg) kp[reg] = (bf16)accK[kb][nt][reg];
                *(bf16x4*)(Kg + base + (size_t)keyK * 64 + nt * 16 + quad * 4) = kp;
                // V (normal): accV[kb][nt][reg] = V[key=key0+wave*32+kb*16+quad*4+reg][e=nt*16+l15]
                const int kv0 = key0 + wave * 32 + kb * 16 + quad * 4;
                bf16x4 vp;
#pragma unroll
                for (int reg = 0; reg < 4; ++reg) vp[reg] = (bf16)accV[kb][nt][reg];
                *(bf16x4*)(Vg + base + (size_t)(nt * 16 + l15) * 512 + kv0) = vp;
            }
    }
}

// ---------------------------------------------------------------------------
// Kernel 1: flash attention over precomputed K/V. Grid 1024 (bh = blk&127,
// qc = blk>>7, 64 queries each). LDS 40960 B -> 4 blocks/CU = 4 waves/SIMD
// (2x R2's TLP). Per tile: single barrier, gld16 next tile issued after it
// (latency hidden under S/exp/PV compute). No X / K/V-MFMA in the loop.
// ---------------------------------------------------------------------------
__global__ __launch_bounds__(256, 4) void attn(
    const float* __restrict__ X, const int* __restrict__ mask,
    const bf16* __restrict__ WqT, const float* __restrict__ bq,
    const float* __restrict__ bv, const bf16* __restrict__ Kg,
    const bf16* __restrict__ Vg, bf16* __restrict__ Ob)
{
    __shared__ __align__(16) char smem[40960];
    // Ks dbuf @0/8192: [key64][64] swz; Vts dbuf @16384/24576: [e64][64] swz;
    // Pl @32768: 4x wave strip [16 q][64] swz. Aliases: Wqs=Ks buf0, Xq=Pl,
    // Q-stage=Pl strips, Ostage=smem base (p72).
    const int bh = blockIdx.x & 127, q0 = (blockIdx.x >> 7) * 64;
    const int b = bh >> 4, h = bh & 15;
    const int tid = threadIdx.x, wave = tid >> 6, lane = tid & 63;
    const int quad = lane >> 4, l15 = lane & 15;
    const int lr = lane >> 3, lc = lane & 7;
    const int csw = (lc ^ lr) * 8;
    const size_t kvbase = (size_t)bh * 32768;

    bf16* Wqs = (bf16*)smem;
    bf16* Xq  = (bf16*)(smem + 32768);
    bf16* Plw = (bf16*)(smem + 32768 + wave * 2048);

    float bqr[4], bvr[4];
#pragma unroll
    for (int nt = 0; nt < 4; ++nt) {
        bqr[nt] = bq[h * DH + nt * 16 + l15];
        bvr[nt] = bv[h * DH + nt * 16 + l15];
    }

    int4 mvc[4], mvn[4];
#pragma unroll
    for (int nt = 0; nt < 4; ++nt)
        mvc[nt] = *(const int4*)&mask[(size_t)b * T + nt * 16 + quad * 4];

    // setup: Wq gld16 + X q-tile (64 rows) -> LDS
#pragma unroll
    for (int j = 0; j < 2; ++j)
        gld16(WqT + (size_t)h * 4096 + (j * 32 + wave * 8 + lr) * 64 + csw,
              &Wqs[(j * 32 + wave * 8) * 64]);
    for (int i = tid; i < 512; i += 256) {
        const int row = i >> 3, c = i & 7;
        const float* src = X + (size_t)(b * T + q0 + row) * D + h * DH + c * 8;
        const float4 x0 = *(const float4*)src;
        const float4 x1 = *(const float4*)(src + 4);
        bf16x8 t;
        t[0] = (bf16)x0.x; t[1] = (bf16)x0.y; t[2] = (bf16)x0.z; t[3] = (bf16)x0.w;
        t[4] = (bf16)x1.x; t[5] = (bf16)x1.y; t[6] = (bf16)x1.z; t[7] = (bf16)x1.w;
        *(bf16x8*)&Xq[row * 64 + ((c ^ (row & 7)) * 8)] = t;
    }
    __syncthreads();   // drains Wqs gld16; Xq visible

    // Q = Xq @ WqT (16 q per wave)
    f32x4 accQ[4] = {};
#pragma unroll
    for (int ks = 0; ks < 2; ++ks) {
        const bf16x8 a8 = *(const bf16x8*)&Xq[(wave * 16 + l15) * 64 + (((ks * 4 + quad) ^ (l15 & 7)) * 8)];
#pragma unroll
        for (int nt = 0; nt < 4; ++nt) {
            const bf16x8 w8 = *(const bf16x8*)&Wqs[(nt * 16 + l15) * 64 + (((ks * 4 + quad) ^ (l15 & 7)) * 8)];
            accQ[nt] = __builtin_amdgcn_mfma_f32_16x16x32_bf16(a8, w8, accQ[nt], 0, 0, 0);
        }
    }
    __syncthreads();   // Xq & Wqs(Ks buf0) free

    // issue K/V tile 0 while Q roundtrips
    {
        bf16* KsL = (bf16*)smem;
        bf16* VtL = (bf16*)(smem + 16384);
#pragma unroll
        for (int j = 0; j < 2; ++j) {
            const int row = j * 32 + wave * 8 + lr;
            gld16(Kg + kvbase + (size_t)row * 64 + csw, &KsL[(j * 32 + wave * 8) * 64]);
            gld16(Vg + kvbase + (size_t)row * 512 + csw, &VtL[(j * 32 + wave * 8) * 64]);
        }
    }

    // Q C-layout -> own Pl strip (swz [q][e]) -> qf (B-frag rows q)
    const float qs = 0.125f * EXP2SCALE;
#pragma unroll
    for (int nt = 0; nt < 4; ++nt)
#pragma unroll
        for (int reg = 0; reg < 4; ++reg) {
            const int q = quad * 4 + reg;
            Plw[q * 64 + (((nt * 2 + (l15 >> 3)) ^ (q & 7)) * 8) + (l15 & 7)] =
                (bf16)((accQ[nt][reg] + bqr[nt]) * qs);
        }
    __builtin_amdgcn_wave_barrier();
    bf16x8 qf[2];
#pragma unroll
    for (int ks = 0; ks < 2; ++ks)
        qf[ks] = *(const bf16x8*)&Plw[l15 * 64 + (((ks * 4 + quad) ^ (l15 & 7)) * 8)];
    __builtin_amdgcn_wave_barrier();

    f32x4 acc[4] = {};
    float lsum = 0.f;

    for (int kt = 0; kt < 8; ++kt) {
        const int p = kt & 1;
        __syncthreads();   // drains tile-kt gld16; syncs buffer reuse
        if (kt < 7) {      // issue tile kt+1 into other buffer
            bf16* KsL = (bf16*)(smem + (p ^ 1) * 8192);
            bf16* VtL = (bf16*)(smem + 16384 + (p ^ 1) * 8192);
#pragma unroll
            for (int j = 0; j < 2; ++j) {
                const int row = j * 32 + wave * 8 + lr;
                gld16(Kg + kvbase + (size_t)((kt + 1) * 64 + row) * 64 + csw,
                      &KsL[(j * 32 + wave * 8) * 64]);
                gld16(Vg + kvbase + (size_t)row * 512 + (kt + 1) * 64 + csw,
                      &VtL[(j * 32 + wave * 8) * 64]);
            }
#pragma unroll
            for (int nt = 0; nt < 4; ++nt)
                mvn[nt] = *(const int4*)&mask[(size_t)b * T + (kt + 1) * 64 + nt * 16 + quad * 4];
        }
        bf16* Ks = (bf16*)(smem + p * 8192);
        bf16* Vt = (bf16*)(smem + 16384 + p * 8192);

        // S^T = K Q^T: lane holds S[key=nt*16+quad*4+reg][q=l15]
        f32x4 s[4] = {};
#pragma unroll
        for (int ks = 0; ks < 2; ++ks)
#pragma unroll
            for (int nt = 0; nt < 4; ++nt) {
                const bf16x8 k8 = *(const bf16x8*)&Ks[(nt * 16 + l15) * 64 + (((ks * 4 + quad) ^ (l15 & 7)) * 8)];
                s[nt] = __builtin_amdgcn_mfma_f32_16x16x32_bf16(k8, qf[ks], s[nt], 0, 0, 0);
            }
        // exp2 + packed P write (own strip)
#pragma unroll
        for (int nt = 0; nt < 4; ++nt) {
            const float p0 = (mvc[nt].x > 0) ? exp2f(s[nt][0]) : 0.f;
            const float p1 = (mvc[nt].y > 0) ? exp2f(s[nt][1]) : 0.f;
            const float p2 = (mvc[nt].z > 0) ? exp2f(s[nt][2]) : 0.f;
            const float p3 = (mvc[nt].w > 0) ? exp2f(s[nt][3]) : 0.f;
            lsum += (p0 + p1) + (p2 + p3);
            bf16x4 pp;
            pp[0] = (bf16)p0; pp[1] = (bf16)p1; pp[2] = (bf16)p2; pp[3] = (bf16)p3;
            *(bf16x4*)&Plw[l15 * 64 + (((nt * 2 + (quad >> 1)) ^ (l15 & 7)) * 8) + (quad & 1) * 4] = pp;
        }
        __builtin_amdgcn_wave_barrier();
        // O += P V
#pragma unroll
        for (int kc = 0; kc < 2; ++kc) {
            const bf16x8 pf = *(const bf16x8*)&Plw[l15 * 64 + (((kc * 4 + quad) ^ (l15 & 7)) * 8)];
#pragma unroll
            for (int nt = 0; nt < 4; ++nt) {
                const bf16x8 vf = *(const bf16x8*)&Vt[(nt * 16 + l15) * 64 + (((kc * 4 + quad) ^ (l15 & 7)) * 8)];
                acc[nt] = __builtin_amdgcn_mfma_f32_16x16x32_bf16(pf, vf, acc[nt], 0, 0, 0);
            }
        }
#pragma unroll
        for (int nt = 0; nt < 4; ++nt) mvc[nt] = mvn[nt];
    }

    __syncthreads();   // all LDS reads done; base region reusable
    // normalize: lane's lsum is for q=l15 over its 16 keys -> reduce quads
    float l = lsum;
    l += __shfl_xor(l, 16);
    l += __shfl_xor(l, 32);
    const float inv = 1.f / l;
    float inv_r[4];
#pragma unroll
    for (int reg = 0; reg < 4; ++reg)
        inv_r[reg] = __shfl(inv, (lane & 48) | (quad * 4 + reg));
    bf16* Ostage = (bf16*)smem;   // 64 x p72
#pragma unroll
    for (int nt = 0; nt < 4; ++nt)
#pragma unroll
        for (int reg = 0; reg < 4; ++reg)
            Ostage[(wave * 16 + quad * 4 + reg) * 72 + nt * 16 + l15] =
                (bf16)(acc[nt][reg] * inv_r[reg] + bvr[nt]);
    __syncthreads();
    for (int i = tid; i < 512; i += 256) {
        const int row = i >> 3, c = (i & 7) * 8;
        *(bf16x8*)(Ob + ((size_t)b * T + q0 + row) * D + h * DH + c) =
            *(const bf16x8*)&Ostage[row * 72 + c];
    }
}

// ---------------------------------------------------------------------------
// Kernel 2: fusion GEMM, 128x128 tile, 512 threads / 8 waves (R2 had 256t ->
// 1 wave/SIMD; now 2 waves/SIMD at the same staging:MFMA ratio).
// ---------------------------------------------------------------------------
__global__ __launch_bounds__(512, 2) void fuse_mfma(
    const bf16* __restrict__ Ob, const bf16* __restrict__ WfT,
    const float* __restrict__ bfv, float* __restrict__ out)
{
    __shared__ __align__(16) char smem[65536];
    const int col0 = blockIdx.x * 128;
    const int row0 = blockIdx.y * 128;
    const int tid = threadIdx.x, wave = tid >> 6, lane = tid & 63;
    const int quad = lane >> 4, l15 = lane & 15;
    const int lr = lane >> 3, lc = lane & 7;
    const int csw = (lc ^ lr) * 8;
    const int wm = (wave >> 1) * 32, wn = (wave & 1) * 64;

    f32x4 acc[2][4] = {};

    auto stage = [&](int k0, int buf) {
        bf16* As = (bf16*)(smem + buf * 16384);
        bf16* Bs = (bf16*)(smem + 32768 + buf * 16384);
#pragma unroll
        for (int j = 0; j < 2; ++j) {
            const int row = j * 64 + wave * 8 + lr;
            gld16(Ob + (size_t)(row0 + row) * D + k0 + csw, &As[(j * 64 + wave * 8) * 64]);
            gld16(WfT + (size_t)(col0 + row) * D + k0 + csw, &Bs[(j * 64 + wave * 8) * 64]);
        }
    };

    stage(0, 0);
    __syncthreads();

    for (int i = 0; i < 16; ++i) {
        const int buf = i & 1;
        if (i < 15) stage((i + 1) * 64, buf ^ 1);   // overlap with compute
        bf16* As = (bf16*)(smem + buf * 16384);
        bf16* Bs = (bf16*)(smem + 32768 + buf * 16384);
#pragma unroll
        for (int ks = 0; ks < 2; ++ks) {
            bf16x8 af[2], bfr[4];
#pragma unroll
            for (int mt = 0; mt < 2; ++mt)
                af[mt] = *(const bf16x8*)&As[(wm + mt * 16 + l15) * 64 + (((ks * 4 + quad) ^ (l15 & 7)) * 8)];
#pragma unroll
            for (int nt = 0; nt < 4; ++nt)
                bfr[nt] = *(const bf16x8*)&Bs[(wn + nt * 16 + l15) * 64 + (((ks * 4 + quad) ^ (l15 & 7)) * 8)];
#pragma unroll
            for (int mt = 0; mt < 2; ++mt)
#pragma unroll
                for (int nt = 0; nt < 4; ++nt)
                    acc[mt][nt] = __builtin_amdgcn_mfma_f32_16x16x32_bf16(af[mt], bfr[nt], acc[mt][nt], 0, 0, 0);
        }
        __syncthreads();   // next-buf loads landed; cur-buf reads done
    }

    // Epilogue: +bias -> LDS fp32 p68 -> float4 stores; two 64-col passes.
    float* Ofs = (float*)smem;
    float bias[4];
#pragma unroll
    for (int nt = 0; nt < 4; ++nt) bias[nt] = bfv[col0 + wn + nt * 16 + l15];
#pragma unroll
    for (int cp = 0; cp < 2; ++cp) {
        if (cp) __syncthreads();
        if ((wave & 1) == cp) {
#pragma unroll
            for (int mt = 0; mt < 2; ++mt)
#pragma unroll
                for (int reg = 0; reg < 4; ++reg) {
                    const int row = wm + mt * 16 + quad * 4 + reg;
#pragma unroll
                    for (int nt = 0; nt < 4; ++nt)
                        Ofs[row * 68 + nt * 16 + l15] = acc[mt][nt][reg] + bias[nt];
                }
        }
        __syncthreads();
        for (int i = tid; i < 2048; i += 512) {
            const int row = i >> 4, c = (i & 15) * 4;
            *(float4*)(out + (size_t)(row0 + row) * D + col0 + cp * 64 + c) =
                *(const float4*)&Ofs[row * 68 + c];
        }
    }
}

// ---------------------------------------------------------------------------
extern "C" void kernel_launch(void* const* d_in, const int* in_sizes, int n_in,
                              void* d_out, int out_size, void* d_ws, size_t ws_size,
                              hipStream_t stream) {
    const float* X   = (const float*)d_in[0];
    const int* mask  = (const int*)d_in[1];
    const float* Wq  = (const float*)d_in[2];
    const float* bq  = (const float*)d_in[3];
    const float* Wk  = (const float*)d_in[4];
    const float* bk  = (const float*)d_in[5];   // cancels in softmax (exact)
    const float* Wv  = (const float*)d_in[6];
    const float* bv  = (const float*)d_in[7];
    const float* Wf  = (const float*)d_in[8];
    const float* bfv = (const float*)d_in[9];
    float* out = (float*)d_out;
    (void)bk;

    bf16* wsb = (bf16*)d_ws;
    const size_t QN = (size_t)B * H * T * DH;   // 4,194,304
    bf16* Ob  = wsb;
    bf16* WfT = wsb + QN;                       // 1,048,576
    bf16* WqT = WfT + (size_t)D * D;            // 65,536
    bf16* Kg  = WqT + (size_t)H * DH * DH;      // 4,194,304
    bf16* Vg  = Kg + QN;                        // 4,194,304

    prep<<<dim3(784), 256, 0, stream>>>(X, Wq, Wk, Wv, Wf, WqT, WfT, Kg, Vg);
    attn<<<dim3(1024), 256, 0, stream>>>(X, mask, WqT, bq, bv, Kg, Vg, Ob);
    fuse_mfma<<<dim3(D / 128, (B * T) / 128), 512, 0, stream>>>(Ob, WfT, bfv, out);
}

// Round 4
// 125.990 us; speedup vs baseline: 1.0617x; 1.0617x over previous
//
#include <hip/hip_runtime.h>
#include <math.h>

#define B 8
#define T 512
#define D 1024
#define H 16
#define DH 64

typedef __bf16 bf16;
typedef __attribute__((ext_vector_type(8))) __bf16 bf16x8;
typedef __attribute__((ext_vector_type(4))) __bf16 bf16x4;
typedef __attribute__((ext_vector_type(4))) float f32x4;

// Async global->LDS, 16 B per lane. LDS dest = wave-uniform base + lane*16.
__device__ __forceinline__ void gld16(const void* g, void* l) {
    __builtin_amdgcn_global_load_lds(
        (const __attribute__((address_space(1))) void*)g,
        (__attribute__((address_space(3))) void*)l, 16, 0, 0);
}

// MFMA 16x16x32 bf16 layouts (HW-verified per guide m89/m120):
//   A[m][k]: m = lane&15, k = (lane>>4)*8 + j
//   B[k][n]: n = lane&15, k = (lane>>4)*8 + j   (same lane map as A!)
//   C/D    : col = lane&15, row = (lane>>4)*4 + reg
// => swapping mfma operand order transposes D without touching fragments.
// W LDS tiles are XOR-chunk swizzled: element (e,d) of a [e][d] 64x64 tile
// lives at e*64 + ((d>>3 ^ (e&7))*8) + (d&7).
//
// R4: dispatch-count experiment. The timed iteration is a 15-dispatch cycle
// (fill IDs = 2 mod 15 across rounds); kernel-internal optimizations have
// been invisible for 3 rounds => slots, not execution, dominate. This round
// folds prep into the attention launch (3 -> 2 kernels): attn blocks
// transpose their own head's Wq/Wk/Wv from fp32 in setup; 256 rider blocks
// do the Wf->WfT transpose.

#define EXP2SCALE 1.44269504088896f   // log2(e); folded into Q pre-scale

// ---------------------------------------------------------------------------
// Kernel A: blk<512  -> fused qkv + flash attention (R2-verified structure).
//           blk>=512 -> Wf -> WfT [n][k] bf16 transpose tile (prep fold-in).
// ---------------------------------------------------------------------------
__global__ __launch_bounds__(256, 2) void qkv_attn(
    const float* __restrict__ X, const int* __restrict__ mask,
    const float* __restrict__ Wq, const float* __restrict__ Wk,
    const float* __restrict__ Wv,
    const float* __restrict__ bq, const float* __restrict__ bv,
    const float* __restrict__ Wf, bf16* __restrict__ WfT,
    bf16* __restrict__ Ob)
{
    __shared__ __align__(16) char smem[80384];

    if (blockIdx.x >= 512) {
        // ---- Wf transpose rider blocks (same as old prep, r6-verified) ----
        bf16* Ts = (bf16*)smem;   // 64 x 72
        const int ti = blockIdx.x - 512, tid = threadIdx.x;
        const int k0 = (ti >> 4) * 64, n0 = (ti & 15) * 64;
        for (int i = tid; i < 1024; i += 256) {
            const int k = i >> 4, nq = (i & 15) * 4;
            const float4 w = *(const float4*)(Wf + (size_t)(k0 + k) * D + n0 + nq);
            Ts[(nq + 0) * 72 + k] = (bf16)w.x; Ts[(nq + 1) * 72 + k] = (bf16)w.y;
            Ts[(nq + 2) * 72 + k] = (bf16)w.z; Ts[(nq + 3) * 72 + k] = (bf16)w.w;
        }
        __syncthreads();
        for (int i = tid; i < 512; i += 256) {
            const int n = i >> 3, kc = (i & 7) * 8;
            *(bf16x8*)(WfT + (size_t)(n0 + n) * D + k0 + kc) = *(const bf16x8*)&Ts[n * 72 + kc];
        }
        return;
    }

    bf16* Wks = (bf16*)(smem);                 // 8192, persistent
    bf16* Wvs = (bf16*)(smem + 8192);          // 8192, persistent
    // Ks buffers at 16384 + p*9216 ([key][e] p72); Vts at 34816 + p*9216.
    bf16* Pl  = (bf16*)(smem + 53248);         // 4 wave strips 32x72 (18432)
    bf16* Xkt = (bf16*)(smem + 71680);         // 64x64 swizzled (8192)
    int*  msk = (int*)(smem + 79872);          // 2 x 64 ints
    // setup aliases (dead regions; barriers enforce):
    bf16* Wqs   = (bf16*)(smem + 16384);       // = Ks buf 0
    bf16* Xq    = Pl;                          // 16384 <= 18432
    bf16* Stage = Pl;                          // 128 rows p72 (wave strips)
    bf16* Ostage = Pl;

    const int bh = blockIdx.x & 127, q0 = (blockIdx.x >> 7) * 128;
    const int b = bh >> 4, h = bh & 15;
    const int tid = threadIdx.x, wave = tid >> 6, lane = tid & 63;
    const int quad = lane >> 4, l15 = lane & 15;

    // X key-tile prefetch addressing (wave w -> keys w*16..w*16+15)
    const int pkrow = wave * 16 + (lane >> 2);
    const int pc0 = (lane & 3) * 2;

    float bqr[4], bvr[4];
#pragma unroll
    for (int nt = 0; nt < 4; ++nt) {
        bqr[nt] = bq[h * DH + nt * 16 + l15];
        bvr[nt] = bv[h * DH + nt * 16 + l15];
    }

    // ---- prefetch tile 0 (X rows + mask) into registers ----
    float4 px0, px1, px2, px3;
    {
        const float* src = X + (size_t)(b * T + pkrow) * D + h * DH + pc0 * 8;
        px0 = *(const float4*)src; px1 = *(const float4*)(src + 4);
        px2 = *(const float4*)(src + 8); px3 = *(const float4*)(src + 12);
    }
    int mreg = (tid < 64) ? mask[(size_t)b * T + tid] : 0;

    // ---- setup: W transpose fp32 -> swizzled [e][d] bf16 LDS (inline prep) ----
    for (int i = tid; i < 1024; i += 256) {
        const int d = i >> 4, eq4 = (i & 15) * 4;
        const int cw = ((d >> 3)) * 8 + (d & 7);   // chunk base before XOR
        const float4 wq4 = *(const float4*)(Wq + (size_t)h * 4096 + d * 64 + eq4);
        const float4 wk4 = *(const float4*)(Wk + (size_t)h * 4096 + d * 64 + eq4);
        const float4 wv4 = *(const float4*)(Wv + (size_t)h * 4096 + d * 64 + eq4);
#pragma unroll
        for (int j = 0; j < 4; ++j) {
            const int e = eq4 + j;
            const int idx = e * 64 + (((d >> 3) ^ (e & 7)) * 8) + (d & 7);
            Wqs[idx] = (bf16)((const float*)&wq4)[j];
            Wks[idx] = (bf16)((const float*)&wk4)[j];
            Wvs[idx] = (bf16)((const float*)&wv4)[j];
        }
        (void)cw;
    }
    for (int i = tid; i < 1024; i += 256) {
        const int row = i >> 3, c = i & 7;
        const float* src = X + (size_t)(b * T + q0 + row) * D + h * DH + c * 8;
        const float4 x0 = *(const float4*)src;
        const float4 x1 = *(const float4*)(src + 4);
        bf16x8 t;
        t[0] = (bf16)x0.x; t[1] = (bf16)x0.y; t[2] = (bf16)x0.z; t[3] = (bf16)x0.w;
        t[4] = (bf16)x1.x; t[5] = (bf16)x1.y; t[6] = (bf16)x1.z; t[7] = (bf16)x1.w;
        *(bf16x8*)&Xq[row * 64 + ((c ^ (row & 7)) * 8)] = t;
    }
    __syncthreads();

    // ---- Q = Xq @ WqT (+bias, x 0.125*log2e), C-layout -> Stage -> qf ----
    {
        f32x4 accQ[2][4] = {};
#pragma unroll
        for (int ks = 0; ks < 2; ++ks) {
            bf16x8 af[2], bfr[4];
#pragma unroll
            for (int mt = 0; mt < 2; ++mt) {
                const int row = wave * 32 + mt * 16 + l15;
                af[mt] = *(const bf16x8*)&Xq[row * 64 + (((ks * 4 + quad) ^ (l15 & 7)) * 8)];
            }
#pragma unroll
            for (int nt = 0; nt < 4; ++nt)
                bfr[nt] = *(const bf16x8*)&Wqs[(nt * 16 + l15) * 64 + (((ks * 4 + quad) ^ (l15 & 7)) * 8)];
#pragma unroll
            for (int mt = 0; mt < 2; ++mt)
#pragma unroll
                for (int nt = 0; nt < 4; ++nt)
                    accQ[mt][nt] = __builtin_amdgcn_mfma_f32_16x16x32_bf16(af[mt], bfr[nt], accQ[mt][nt], 0, 0, 0);
        }
        __syncthreads();   // Xq/Wqs reads done everywhere
        const float qs = 0.125f * EXP2SCALE;
#pragma unroll
        for (int mt = 0; mt < 2; ++mt)
#pragma unroll
            for (int nt = 0; nt < 4; ++nt)
#pragma unroll
                for (int reg = 0; reg < 4; ++reg)
                    Stage[(wave * 32 + mt * 16 + quad * 4 + reg) * 72 + nt * 16 + l15] =
                        (bf16)((accQ[mt][nt][reg] + bqr[nt]) * qs);
        __builtin_amdgcn_wave_barrier();
    }
    bf16x8 qf[2][2];
#pragma unroll
    for (int mt = 0; mt < 2; ++mt)
#pragma unroll
        for (int ks = 0; ks < 2; ++ks)
            qf[mt][ks] = *(const bf16x8*)&Stage[(wave * 32 + mt * 16 + l15) * 72 + ks * 32 + quad * 8];

    f32x4 acc[2][4] = {};
    float lst2[2] = {0.f, 0.f};

    // ---- K-loop: 8 tiles of 64 keys, pipelined, ONE barrier per tile ----
    for (int kt = 0; kt < 8; ++kt) {
        const int p = kt & 1;
        bf16* Ks  = (bf16*)(smem + 16384 + p * 9216);
        bf16* Vts = (bf16*)(smem + 34816 + p * 9216);

        // stage prefetched X -> Xkt (wave-local), msk -> LDS
        {
            bf16x8 t0, t1;
            t0[0] = (bf16)px0.x; t0[1] = (bf16)px0.y; t0[2] = (bf16)px0.z; t0[3] = (bf16)px0.w;
            t0[4] = (bf16)px1.x; t0[5] = (bf16)px1.y; t0[6] = (bf16)px1.z; t0[7] = (bf16)px1.w;
            t1[0] = (bf16)px2.x; t1[1] = (bf16)px2.y; t1[2] = (bf16)px2.z; t1[3] = (bf16)px2.w;
            t1[4] = (bf16)px3.x; t1[5] = (bf16)px3.y; t1[6] = (bf16)px3.z; t1[7] = (bf16)px3.w;
            *(bf16x8*)&Xkt[pkrow * 64 + ((pc0 ^ (pkrow & 7)) * 8)] = t0;
            *(bf16x8*)&Xkt[pkrow * 64 + (((pc0 + 1) ^ (pkrow & 7)) * 8)] = t1;
            if (tid < 64) msk[p * 64 + tid] = mreg;
        }
        __builtin_amdgcn_wave_barrier();   // wave-local Xkt write->read

        // issue prefetch for tile kt+1 (covers full tile compute)
        if (kt < 7) {
            const float* src = X + (size_t)(b * T + (kt + 1) * 64 + pkrow) * D + h * DH + pc0 * 8;
            px0 = *(const float4*)src; px1 = *(const float4*)(src + 4);
            px2 = *(const float4*)(src + 8); px3 = *(const float4*)(src + 12);
            if (tid < 64) mreg = mask[(size_t)b * T + (kt + 1) * 64 + tid];
        }

        // K/V tiles via MFMA (wave computes its own 16 keys).
        // K: swapped operands -> D[e][key], reg runs along e -> b64 pack.
        // V: normal operands  -> D[key][e] -> b64 pack into [e][key] store.
        {
            bf16x8 afkv[2];
#pragma unroll
            for (int ks = 0; ks < 2; ++ks)
                afkv[ks] = *(const bf16x8*)&Xkt[(wave * 16 + l15) * 64 + (((ks * 4 + quad) ^ (l15 & 7)) * 8)];
            f32x4 accK[4] = {}, accV[4] = {};
#pragma unroll
            for (int ks = 0; ks < 2; ++ks)
#pragma unroll
                for (int nt = 0; nt < 4; ++nt) {
                    const bf16x8 bk8 = *(const bf16x8*)&Wks[(nt * 16 + l15) * 64 + (((ks * 4 + quad) ^ (l15 & 7)) * 8)];
                    accK[nt] = __builtin_amdgcn_mfma_f32_16x16x32_bf16(bk8, afkv[ks], accK[nt], 0, 0, 0);
                    const bf16x8 bv8 = *(const bf16x8*)&Wvs[(nt * 16 + l15) * 64 + (((ks * 4 + quad) ^ (l15 & 7)) * 8)];
                    accV[nt] = __builtin_amdgcn_mfma_f32_16x16x32_bf16(afkv[ks], bv8, accV[nt], 0, 0, 0);
                }
#pragma unroll
            for (int nt = 0; nt < 4; ++nt) {
                bf16x4 kp;
#pragma unroll
                for (int reg = 0; reg < 4; ++reg) kp[reg] = (bf16)accK[nt][reg];
                *(bf16x4*)&Ks[(wave * 16 + l15) * 72 + nt * 16 + quad * 4] = kp;
                bf16x4 vp;
#pragma unroll
                for (int reg = 0; reg < 4; ++reg) vp[reg] = (bf16)accV[nt][reg];
                *(bf16x4*)&Vts[(nt * 16 + l15) * 72 + wave * 16 + quad * 4] = vp;
            }
        }
        __syncthreads();   // the only block barrier: K/V (+msk) visible

        // S^T = K Q^T (swapped): lane holds S[key=nt*16+quad*4+reg][q=mt*16+l15]
        bf16* Plw = Pl + wave * (32 * 72);
        {
            bf16x8 kf[4][2];
#pragma unroll
            for (int nt = 0; nt < 4; ++nt)
#pragma unroll
                for (int ks = 0; ks < 2; ++ks)
                    kf[nt][ks] = *(const bf16x8*)&Ks[(nt * 16 + l15) * 72 + ks * 32 + quad * 8];
            int4 mv4[4];
#pragma unroll
            for (int nt = 0; nt < 4; ++nt)
                mv4[nt] = *(const int4*)&msk[p * 64 + nt * 16 + quad * 4];
#pragma unroll
            for (int mt = 0; mt < 2; ++mt) {
                f32x4 s[4] = {};
#pragma unroll
                for (int ks = 0; ks < 2; ++ks)
#pragma unroll
                    for (int nt = 0; nt < 4; ++nt)
                        s[nt] = __builtin_amdgcn_mfma_f32_16x16x32_bf16(kf[nt][ks], qf[mt][ks], s[nt], 0, 0, 0);
#pragma unroll
                for (int nt = 0; nt < 4; ++nt) {
                    bf16x4 pp;
                    const float p0 = (mv4[nt].x > 0) ? exp2f(s[nt][0]) : 0.f;
                    const float p1 = (mv4[nt].y > 0) ? exp2f(s[nt][1]) : 0.f;
                    const float p2 = (mv4[nt].z > 0) ? exp2f(s[nt][2]) : 0.f;
                    const float p3 = (mv4[nt].w > 0) ? exp2f(s[nt][3]) : 0.f;
                    lst2[mt] += (p0 + p1) + (p2 + p3);
                    pp[0] = (bf16)p0; pp[1] = (bf16)p1; pp[2] = (bf16)p2; pp[3] = (bf16)p3;
                    *(bf16x4*)&Plw[(mt * 16 + l15) * 72 + nt * 16 + quad * 4] = pp;
                }
            }
        }
        __builtin_amdgcn_wave_barrier();   // wave-local P write->read

        // O += P V
#pragma unroll
        for (int kc = 0; kc < 2; ++kc) {
            const bf16x8 pf0 = *(const bf16x8*)&Plw[(l15) * 72 + kc * 32 + quad * 8];
            const bf16x8 pf1 = *(const bf16x8*)&Plw[(16 + l15) * 72 + kc * 32 + quad * 8];
#pragma unroll
            for (int nt = 0; nt < 4; ++nt) {
                const bf16x8 vf = *(const bf16x8*)&Vts[(nt * 16 + l15) * 72 + kc * 32 + quad * 8];
                acc[0][nt] = __builtin_amdgcn_mfma_f32_16x16x32_bf16(pf0, vf, acc[0][nt], 0, 0, 0);
                acc[1][nt] = __builtin_amdgcn_mfma_f32_16x16x32_bf16(pf1, vf, acc[1][nt], 0, 0, 0);
            }
        }
    }

    // ---- epilogue: reduce l across quads, redistribute, +bv, store ----
    __builtin_amdgcn_wave_barrier();
    float inv_r[2][4];
#pragma unroll
    for (int mt = 0; mt < 2; ++mt) {
        float l = lst2[mt];
        l += __shfl_xor(l, 16);
        l += __shfl_xor(l, 32);
        const float inv = 1.f / l;
#pragma unroll
        for (int reg = 0; reg < 4; ++reg)
            inv_r[mt][reg] = __shfl(inv, (lane & 48) | (quad * 4 + reg));
    }
#pragma unroll
    for (int mt = 0; mt < 2; ++mt)
#pragma unroll
        for (int reg = 0; reg < 4; ++reg) {
            const int row = wave * 32 + mt * 16 + quad * 4 + reg;   // own strip
#pragma unroll
            for (int nt = 0; nt < 4; ++nt)
                Ostage[row * 72 + nt * 16 + l15] =
                    (bf16)(acc[mt][nt][reg] * inv_r[mt][reg] + bvr[nt]);
        }
    __syncthreads();
    for (int i = tid; i < 1024; i += 256) {
        const int row = i >> 3, c = (i & 7) * 8;
        *(bf16x8*)(Ob + ((size_t)b * T + q0 + row) * D + h * DH + c) =
            *(const bf16x8*)&Ostage[row * 72 + c];
    }
}

// ---------------------------------------------------------------------------
// Kernel B: fusion GEMM, double-buffered BK=64, 128M x 128N tile
// (R2-verified verbatim).
// ---------------------------------------------------------------------------
__global__ __launch_bounds__(256, 2) void fuse_mfma(
    const bf16* __restrict__ Ob, const bf16* __restrict__ WfT,
    const float* __restrict__ bfv, float* __restrict__ out)
{
    __shared__ __align__(16) char smem[65536];

    const int col0 = blockIdx.x * 128;
    const int row0 = blockIdx.y * 128;
    const int tid = threadIdx.x, wave = tid >> 6, lane = tid & 63;
    const int quad = lane >> 4, l15 = lane & 15;
    const int lr = lane >> 3, lc = lane & 7;
    const int wm = wave * 32;

    f32x4 acc[2][8] = {};

    auto stage = [&](int k0, int buf) {
        bf16* As = (bf16*)(smem + buf * 16384);
        bf16* Bs = (bf16*)(smem + 32768 + buf * 16384);
#pragma unroll
        for (int j = 0; j < 4; ++j) {
            const int row = wm + j * 8 + lr;
            gld16(Ob + (size_t)(row0 + row) * D + k0 + ((lc ^ (row & 7)) * 8),
                  &As[(wm + j * 8) * 64]);
            gld16(WfT + (size_t)(col0 + row) * D + k0 + ((lc ^ (row & 7)) * 8),
                  &Bs[(wm + j * 8) * 64]);
        }
    };

    stage(0, 0);
    __syncthreads();

    for (int i = 0; i < 16; ++i) {
        const int buf = i & 1;
        if (i < 15) stage((i + 1) * 64, buf ^ 1);   // overlap with compute
        bf16* As = (bf16*)(smem + buf * 16384);
        bf16* Bs = (bf16*)(smem + 32768 + buf * 16384);
#pragma unroll
        for (int ks = 0; ks < 2; ++ks) {
            bf16x8 af[2], bfr[8];
#pragma unroll
            for (int mt = 0; mt < 2; ++mt) {
                const int row = wm + mt * 16 + l15;
                af[mt] = *(const bf16x8*)&As[row * 64 + (((ks * 4 + quad) ^ (l15 & 7)) * 8)];
            }
#pragma unroll
            for (int nt = 0; nt < 8; ++nt)
                bfr[nt] = *(const bf16x8*)&Bs[(nt * 16 + l15) * 64 + (((ks * 4 + quad) ^ (l15 & 7)) * 8)];
#pragma unroll
            for (int mt = 0; mt < 2; ++mt)
#pragma unroll
                for (int nt = 0; nt < 8; ++nt)
                    acc[mt][nt] = __builtin_amdgcn_mfma_f32_16x16x32_bf16(af[mt], bfr[nt], acc[mt][nt], 0, 0, 0);
        }
        __syncthreads();   // next-buf loads landed; cur-buf reads done
    }

    // Epilogue: +bias -> LDS fp32 p68 -> float4 stores; two 64-col passes.
    float* Ofs = (float*)smem;
    float bias[8];
#pragma unroll
    for (int nt = 0; nt < 8; ++nt) bias[nt] = bfv[col0 + nt * 16 + l15];
#pragma unroll
    for (int cp = 0; cp < 2; ++cp) {
        if (cp) __syncthreads();   // pass-0 stores done before overwrite
#pragma unroll
        for (int mt = 0; mt < 2; ++mt)
#pragma unroll
            for (int reg = 0; reg < 4; ++reg) {
                const int row = wm + mt * 16 + quad * 4 + reg;
#pragma unroll
                for (int nn = 0; nn < 4; ++nn)
                    Ofs[row * 68 + nn * 16 + l15] = acc[mt][cp * 4 + nn][reg] + bias[cp * 4 + nn];
            }
        __syncthreads();
        for (int i = tid; i < 2048; i += 256) {
            const int row = i >> 4, c = (i & 15) * 4;
            *(float4*)(out + (size_t)(row0 + row) * D + col0 + cp * 64 + c) =
                *(const float4*)&Ofs[row * 68 + c];
        }
    }
}

// ---------------------------------------------------------------------------
extern "C" void kernel_launch(void* const* d_in, const int* in_sizes, int n_in,
                              void* d_out, int out_size, void* d_ws, size_t ws_size,
                              hipStream_t stream) {
    const float* X   = (const float*)d_in[0];
    const int* mask  = (const int*)d_in[1];
    const float* Wq  = (const float*)d_in[2];
    const float* bq  = (const float*)d_in[3];
    const float* Wk  = (const float*)d_in[4];
    const float* bk  = (const float*)d_in[5];   // cancels in softmax (exact)
    const float* Wv  = (const float*)d_in[6];
    const float* bv  = (const float*)d_in[7];
    const float* Wf  = (const float*)d_in[8];
    const float* bfv = (const float*)d_in[9];
    float* out = (float*)d_out;
    (void)bk;

    bf16* wsb = (bf16*)d_ws;
    const size_t QN = (size_t)B * H * T * DH;   // 4,194,304
    bf16* Ob  = wsb;
    bf16* WfT = wsb + QN;                       // 1,048,576

    qkv_attn<<<dim3(768), 256, 0, stream>>>(X, mask, Wq, Wk, Wv, bq, bv, Wf, WfT, Ob);
    fuse_mfma<<<dim3(D / 128, (B * T) / 128), 256, 0, stream>>>(Ob, WfT, bfv, out);
}